// Round 5
// baseline (600.653 us; speedup 1.0000x reference)
//
#include <hip/hip_runtime.h>

#define T_TOK 8192
#define D_IN  1024
#define H_DIM 2048
#define DOUT_ 1024
#define NEXP  8
#define NPAIR 16384
#define BM 128
#define BN 128
#define BN2 256
#define BK 32
#define MAX_TILES 136

using bf16x8 = __attribute__((ext_vector_type(8))) __bf16;
using f32x4  = __attribute__((ext_vector_type(4))) float;

__device__ __forceinline__ unsigned short f2bf(float f) {
  unsigned int u = __float_as_uint(f);
  u += 0x7FFFu + ((u >> 16) & 1u);   // RNE
  return (unsigned short)(u >> 16);
}

__device__ __forceinline__ float bf2f(unsigned short b) {
  return __uint_as_float((unsigned int)b << 16);
}

__device__ __forceinline__ void gload16(const void* g, void* l) {
  __builtin_amdgcn_global_load_lds(
      (const __attribute__((address_space(1))) void*)g,
      (__attribute__((address_space(3))) void*)l, 16, 0, 0);
}

// Derive this block's (expert, tileStart, segBase, segN) from cnt[8] in
// registers (no meta-table cross-kernel communication).
struct TileInfo { int e, ts, segBase, segN; };
__device__ __forceinline__ bool tile_lookup(const int* __restrict__ cnt, int by, TileInfo& ti) {
  int tp = 0, acc = 0;
  ti.e = -1;
#pragma unroll
  for (int e = 0; e < NEXP; ++e) {
    int c = cnt[e];
    int nt = (c + BM - 1) / BM;
    if (ti.e < 0 && by < tp + nt) { ti.e = e; ti.ts = (by - tp) * BM; ti.segBase = acc; ti.segN = c; }
    tp += nt; acc += c;
  }
  return ti.e >= 0;
}

// ---------------- conversion fp32 -> bf16 ----------------
__global__ void convert_kernel(const float* __restrict__ x, const float* __restrict__ wg,
                               const float* __restrict__ wu, const float* __restrict__ wd,
                               unsigned short* __restrict__ xb, unsigned short* __restrict__ wgb,
                               unsigned short* __restrict__ wub, unsigned short* __restrict__ wdb) {
  const long long nx = (long long)T_TOK * D_IN;
  const long long nw = (long long)NEXP * H_DIM * D_IN;
  const long long nd = (long long)NEXP * DOUT_ * H_DIM;
  const long long tot4 = (nx + 2 * nw + nd) >> 2;
  for (long long i = (long long)blockIdx.x * blockDim.x + threadIdx.x; i < tot4;
       i += (long long)gridDim.x * blockDim.x) {
    long long e = i << 2;
    const float* s; unsigned short* d; long long o;
    if (e < nx)              { s = x;  d = xb;  o = e; }
    else if (e < nx + nw)    { s = wg; d = wgb; o = e - nx; }
    else if (e < nx + 2*nw)  { s = wu; d = wub; o = e - nx - nw; }
    else                     { s = wd; d = wdb; o = e - nx - 2*nw; }
    float4 v = *(const float4*)(s + o);
    ushort4 b;
    b.x = f2bf(v.x); b.y = f2bf(v.y); b.z = f2bf(v.z); b.w = f2bf(v.w);
    *(ushort4*)(d + o) = b;
  }
}

// ---------------- dispatch build ----------------
__global__ void count_kernel(const int* __restrict__ idx, int* __restrict__ cnt) {
  int i = blockIdx.x * blockDim.x + threadIdx.x;
  if (i < NPAIR) atomicAdd(&cnt[idx[i]], 1);
}

__global__ void fill_kernel(const int* __restrict__ idx, const float* __restrict__ w,
                            const int* __restrict__ cnt, int* __restrict__ fill,
                            int* __restrict__ rows, float* __restrict__ wts,
                            int* __restrict__ inv) {
  int i = blockIdx.x * blockDim.x + threadIdx.x;
  if (i < NPAIR) {
    int e = idx[i];
    int base = 0, acc = 0;
#pragma unroll
    for (int k = 0; k < NEXP; ++k) {
      if (k == e) base = acc;
      acc += cnt[k];
    }
    int p = atomicAdd(&fill[e], 1);
    int pos = base + p;
    rows[pos] = i >> 1;       // token id (K=2)
    wts[pos] = w[i];
    inv[i] = pos;
  }
}

// ---------------- GEMM1: h = silu(x@Wg^T) * (x@Wu^T) ----------------
__launch_bounds__(256, 3)
__global__ void gemm1_kernel(const unsigned short* __restrict__ xb,
                             const unsigned short* __restrict__ wgb,
                             const unsigned short* __restrict__ wub,
                             const int* __restrict__ cnt, const int* __restrict__ rows,
                             unsigned short* __restrict__ hbuf) {
  TileInfo ti;
  if (!tile_lookup(cnt, blockIdx.y, ti)) return;
  const int tid = threadIdx.x;
  const int e = ti.e, ts = ti.ts, segBase = ti.segBase, segN = ti.segN;
  const int ncol0 = blockIdx.x * BN;

  __shared__ unsigned short lds[2][3][BM][BK];   // A, Bg, Bu double-buffered: 48 KiB
  __shared__ int rows_s[BM];

  if (tid < BM) {
    int r = ts + tid;
    rows_s[tid] = rows[segBase + (r < segN ? r : 0)];
  }
  __syncthreads();

  const int r0 = tid >> 2, r1 = 64 + (tid >> 2);
  const int kq = (tid & 3) * 8;   // bf16 elements
  const int tok0 = rows_s[r0], tok1 = rows_s[r1];
  const unsigned short* ag0 = xb + (size_t)tok0 * D_IN + kq;
  const unsigned short* ag1 = xb + (size_t)tok1 * D_IN + kq;
  const unsigned short* wge = wgb + (size_t)e * H_DIM * D_IN;
  const unsigned short* wue = wub + (size_t)e * H_DIM * D_IN;
  const unsigned short* bg0 = wge + (size_t)(ncol0 + r0) * D_IN + kq;
  const unsigned short* bg1 = wge + (size_t)(ncol0 + r1) * D_IN + kq;
  const unsigned short* bu0 = wue + (size_t)(ncol0 + r0) * D_IN + kq;
  const unsigned short* bu1 = wue + (size_t)(ncol0 + r1) * D_IN + kq;

#define STAGE1(b, k0) do { \
    gload16(ag0 + (k0), &lds[b][0][r0][kq]); \
    gload16(ag1 + (k0), &lds[b][0][r1][kq]); \
    gload16(bg0 + (k0), &lds[b][1][r0][kq]); \
    gload16(bg1 + (k0), &lds[b][1][r1][kq]); \
    gload16(bu0 + (k0), &lds[b][2][r0][kq]); \
    gload16(bu1 + (k0), &lds[b][2][r1][kq]); \
  } while (0)

  f32x4 gacc[4][4] = {};
  f32x4 uacc[4][4] = {};
  const int lane = tid & 63, wid = tid >> 6;
  const int wm = (wid >> 1) * 64, wn = (wid & 1) * 64;
  const int fr = lane & 15, fq = lane >> 4;

  STAGE1(0, 0);
  __syncthreads();
  for (int kt = 0; kt < D_IN / BK; ++kt) {
    const int cur = kt & 1;
    if (kt + 1 < D_IN / BK) STAGE1(cur ^ 1, (kt + 1) * BK);
    bf16x8 af[4], bgf[4], buf_[4];
#pragma unroll
    for (int mf = 0; mf < 4; ++mf) af[mf]   = *(const bf16x8*)&lds[cur][0][wm + mf * 16 + fr][fq * 8];
#pragma unroll
    for (int nf = 0; nf < 4; ++nf) bgf[nf]  = *(const bf16x8*)&lds[cur][1][wn + nf * 16 + fr][fq * 8];
#pragma unroll
    for (int nf = 0; nf < 4; ++nf) buf_[nf] = *(const bf16x8*)&lds[cur][2][wn + nf * 16 + fr][fq * 8];
#pragma unroll
    for (int mf = 0; mf < 4; ++mf)
#pragma unroll
      for (int nf = 0; nf < 4; ++nf) {
        gacc[mf][nf] = __builtin_amdgcn_mfma_f32_16x16x32_bf16(af[mf], bgf[nf],  gacc[mf][nf], 0, 0, 0);
        uacc[mf][nf] = __builtin_amdgcn_mfma_f32_16x16x32_bf16(af[mf], buf_[nf], uacc[mf][nf], 0, 0, 0);
      }
    __syncthreads();
  }
#undef STAGE1

#pragma unroll
  for (int mf = 0; mf < 4; ++mf)
#pragma unroll
    for (int i = 0; i < 4; ++i) {
      int rloc = wm + mf * 16 + fq * 4 + i;
      int rseg = ts + rloc;
      if (rseg < segN) {
        size_t base = (size_t)(segBase + rseg) * H_DIM + ncol0 + wn;
#pragma unroll
        for (int nf = 0; nf < 4; ++nf) {
          float g = gacc[mf][nf][i], u = uacc[mf][nf][i];
          float h = g / (1.f + __expf(-g)) * u;   // silu(g)*u
          hbuf[base + nf * 16 + fr] = f2bf(h);
        }
      }
    }
}

// ---------------- GEMM2: wout[pos] = w * (h @ Wd^T), BN2=256 (32 MFMA/drain) ----
__launch_bounds__(256, 2)
__global__ void gemm2_kernel(const unsigned short* __restrict__ hbuf,
                             const unsigned short* __restrict__ wdb,
                             const int* __restrict__ cnt,
                             const float* __restrict__ wts, unsigned short* __restrict__ wout) {
  TileInfo ti;
  if (!tile_lookup(cnt, blockIdx.y, ti)) return;
  const int tid = threadIdx.x;
  const int e = ti.e, ts = ti.ts, segBase = ti.segBase, segN = ti.segN;
  const int ncol0 = blockIdx.x * BN2;

  __shared__ unsigned short ldsA[2][BM][BK];    // 16 KiB
  __shared__ unsigned short ldsB[2][BN2][BK];   // 32 KiB

  const int r0 = tid >> 2, r1 = 64 + (tid >> 2);
  const int kq = (tid & 3) * 8;
  int ar0 = ts + r0; if (ar0 >= segN) ar0 = segN - 1;
  int ar1 = ts + r1; if (ar1 >= segN) ar1 = segN - 1;
  const unsigned short* ag0 = hbuf + (size_t)(segBase + ar0) * H_DIM + kq;
  const unsigned short* ag1 = hbuf + (size_t)(segBase + ar1) * H_DIM + kq;
  const unsigned short* wde = wdb + (size_t)e * DOUT_ * H_DIM;
  const unsigned short* bp0 = wde + (size_t)(ncol0 + r0) * H_DIM + kq;
  const unsigned short* bp1 = wde + (size_t)(ncol0 + r0 + 64) * H_DIM + kq;
  const unsigned short* bp2 = wde + (size_t)(ncol0 + r0 + 128) * H_DIM + kq;
  const unsigned short* bp3 = wde + (size_t)(ncol0 + r0 + 192) * H_DIM + kq;

#define STAGE2(b, k0) do { \
    gload16(ag0 + (k0), &ldsA[b][r0][kq]); \
    gload16(ag1 + (k0), &ldsA[b][r1][kq]); \
    gload16(bp0 + (k0), &ldsB[b][r0][kq]); \
    gload16(bp1 + (k0), &ldsB[b][r0 + 64][kq]); \
    gload16(bp2 + (k0), &ldsB[b][r0 + 128][kq]); \
    gload16(bp3 + (k0), &ldsB[b][r0 + 192][kq]); \
  } while (0)

  f32x4 acc[4][8] = {};
  const int lane = tid & 63, wid = tid >> 6;
  const int wm = (wid >> 1) * 64, wn = (wid & 1) * 128;   // 2M x 2N waves
  const int fr = lane & 15, fq = lane >> 4;

  STAGE2(0, 0);
  __syncthreads();
  for (int kt = 0; kt < H_DIM / BK; ++kt) {
    const int cur = kt & 1;
    if (kt + 1 < H_DIM / BK) STAGE2(cur ^ 1, (kt + 1) * BK);
    bf16x8 af[4], bf[8];
#pragma unroll
    for (int mf = 0; mf < 4; ++mf) af[mf] = *(const bf16x8*)&ldsA[cur][wm + mf * 16 + fr][fq * 8];
#pragma unroll
    for (int nf = 0; nf < 8; ++nf) bf[nf] = *(const bf16x8*)&ldsB[cur][wn + nf * 16 + fr][fq * 8];
#pragma unroll
    for (int mf = 0; mf < 4; ++mf)
#pragma unroll
      for (int nf = 0; nf < 8; ++nf)
        acc[mf][nf] = __builtin_amdgcn_mfma_f32_16x16x32_bf16(af[mf], bf[nf], acc[mf][nf], 0, 0, 0);
    __syncthreads();
  }
#undef STAGE2

#pragma unroll
  for (int mf = 0; mf < 4; ++mf)
#pragma unroll
    for (int i = 0; i < 4; ++i) {
      int rloc = wm + mf * 16 + fq * 4 + i;
      int rseg = ts + rloc;
      if (rseg < segN) {
        float w = wts[segBase + rseg];
        unsigned short* obase = wout + (size_t)(segBase + rseg) * DOUT_ + ncol0 + wn;
#pragma unroll
        for (int nf = 0; nf < 8; ++nf)
          obase[nf * 16 + fr] = f2bf(acc[mf][nf][i] * w);
      }
    }
}

// ---------------- combine: out[t] = wout[inv[2t]] + wout[inv[2t+1]] (bf16 in) ----
__global__ void combine_kernel(const unsigned short* __restrict__ wout, const int* __restrict__ inv,
                               float* __restrict__ out) {
  const int total = T_TOK * (DOUT_ / 4);           // 4-elem chunks
  for (int i = blockIdx.x * blockDim.x + threadIdx.x; i < total;
       i += gridDim.x * blockDim.x) {
    int t = i >> 8;                                 // DOUT/4 = 256 chunks per token
    int c4 = (i & 255) << 2;
    int p0 = inv[2 * t], p1 = inv[2 * t + 1];
    ushort4 a = *(const ushort4*)(wout + ((size_t)p0 << 10) + c4);
    ushort4 b = *(const ushort4*)(wout + ((size_t)p1 << 10) + c4);
    float4 r;
    r.x = bf2f(a.x) + bf2f(b.x);
    r.y = bf2f(a.y) + bf2f(b.y);
    r.z = bf2f(a.z) + bf2f(b.z);
    r.w = bf2f(a.w) + bf2f(b.w);
    *(float4*)(out + ((size_t)t << 10) + c4) = r;
  }
}

// ---------------- launch ----------------
extern "C" void kernel_launch(void* const* d_in, const int* in_sizes, int n_in,
                              void* d_out, int out_size, void* d_ws, size_t ws_size,
                              hipStream_t stream) {
  const float* x   = (const float*)d_in[0];
  const int*   idx = (const int*)d_in[1];
  const float* tkw = (const float*)d_in[2];
  const float* wg  = (const float*)d_in[3];
  const float* wu  = (const float*)d_in[4];
  const float* wd  = (const float*)d_in[5];
  float* out = (float*)d_out;

  char* p = (char*)d_ws;
  // wout (bf16, 33.5 MB) aliases xb+wgb: dead after gemm1, rewritten by
  // convert at the start of every call -> deterministic.
  unsigned short* wout = (unsigned short*)p;
  unsigned short* xb   = (unsigned short*)p; p += (size_t)T_TOK * D_IN * 2;
  unsigned short* wgb  = (unsigned short*)p; p += (size_t)NEXP * H_DIM * D_IN * 2;
  unsigned short* wub  = (unsigned short*)p; p += (size_t)NEXP * H_DIM * D_IN * 2;
  unsigned short* wdb  = (unsigned short*)p; p += (size_t)NEXP * DOUT_ * H_DIM * 2;
  unsigned short* hbuf = (unsigned short*)p; p += (size_t)NPAIR * H_DIM * 2;
  int*   rows = (int*)p;   p += NPAIR * 4;
  float* wts  = (float*)p; p += NPAIR * 4;
  int*   inv  = (int*)p;   p += NPAIR * 4;
  int* meta = (int*)p;                 // cnt[8] fill[8]
  int* cnt = meta;
  int* fill = meta + 8;

  hipMemsetAsync(meta, 0, 64, stream);                       // cnt + fill

  convert_kernel<<<2048, 256, 0, stream>>>(x, wg, wu, wd, xb, wgb, wub, wdb);
  count_kernel<<<NPAIR / 256, 256, 0, stream>>>(idx, cnt);
  fill_kernel<<<NPAIR / 256, 256, 0, stream>>>(idx, tkw, cnt, fill, rows, wts, inv);
  gemm1_kernel<<<dim3(H_DIM / BN, MAX_TILES), 256, 0, stream>>>(xb, wgb, wub, cnt, rows, hbuf);
  gemm2_kernel<<<dim3(DOUT_ / BN2, MAX_TILES), 256, 0, stream>>>(hbuf, wdb, cnt, wts, wout);
  combine_kernel<<<2048, 256, 0, stream>>>(wout, inv, out);
}

// Round 6
// 501.213 us; speedup vs baseline: 1.1984x; 1.1984x over previous
//
#include <hip/hip_runtime.h>

#define T_TOK 8192
#define D_IN  1024
#define H_DIM 2048
#define DOUT_ 1024
#define NEXP  8
#define NPAIR 16384
#define BM 128
#define BN 128
#define BK 32
#define MAX_TILES 136

using bf16x8 = __attribute__((ext_vector_type(8))) __bf16;
using f32x4  = __attribute__((ext_vector_type(4))) float;

__device__ __forceinline__ unsigned short f2bf(float f) {
  unsigned int u = __float_as_uint(f);
  u += 0x7FFFu + ((u >> 16) & 1u);   // RNE
  return (unsigned short)(u >> 16);
}

__device__ __forceinline__ float bf2f(unsigned short b) {
  return __uint_as_float((unsigned int)b << 16);
}

__device__ __forceinline__ void gload16(const void* g, void* l) {
  __builtin_amdgcn_global_load_lds(
      (const __attribute__((address_space(1))) void*)g,
      (__attribute__((address_space(3))) void*)l, 16, 0, 0);
}

// Derive this block's (expert, tileStart, segBase, segN) from cnt[8] in
// registers (no meta-table cross-kernel communication).
struct TileInfo { int e, ts, segBase, segN; };
__device__ __forceinline__ bool tile_lookup(const int* __restrict__ cnt, int by, TileInfo& ti) {
  int tp = 0, acc = 0;
  ti.e = -1;
#pragma unroll
  for (int e = 0; e < NEXP; ++e) {
    int c = cnt[e];
    int nt = (c + BM - 1) / BM;
    if (ti.e < 0 && by < tp + nt) { ti.e = e; ti.ts = (by - tp) * BM; ti.segBase = acc; ti.segN = c; }
    tp += nt; acc += c;
  }
  return ti.e >= 0;
}

// ---------------- conversion fp32 -> bf16 ----------------
__global__ void convert_kernel(const float* __restrict__ x, const float* __restrict__ wg,
                               const float* __restrict__ wu, const float* __restrict__ wd,
                               unsigned short* __restrict__ xb, unsigned short* __restrict__ wgb,
                               unsigned short* __restrict__ wub, unsigned short* __restrict__ wdb) {
  const long long nx = (long long)T_TOK * D_IN;
  const long long nw = (long long)NEXP * H_DIM * D_IN;
  const long long nd = (long long)NEXP * DOUT_ * H_DIM;
  const long long tot4 = (nx + 2 * nw + nd) >> 2;
  for (long long i = (long long)blockIdx.x * blockDim.x + threadIdx.x; i < tot4;
       i += (long long)gridDim.x * blockDim.x) {
    long long e = i << 2;
    const float* s; unsigned short* d; long long o;
    if (e < nx)              { s = x;  d = xb;  o = e; }
    else if (e < nx + nw)    { s = wg; d = wgb; o = e - nx; }
    else if (e < nx + 2*nw)  { s = wu; d = wub; o = e - nx - nw; }
    else                     { s = wd; d = wdb; o = e - nx - 2*nw; }
    float4 v = *(const float4*)(s + o);
    ushort4 b;
    b.x = f2bf(v.x); b.y = f2bf(v.y); b.z = f2bf(v.z); b.w = f2bf(v.w);
    *(ushort4*)(d + o) = b;
  }
}

// ---------------- dispatch build ----------------
__global__ void count_kernel(const int* __restrict__ idx, int* __restrict__ cnt) {
  int i = blockIdx.x * blockDim.x + threadIdx.x;
  if (i < NPAIR) atomicAdd(&cnt[idx[i]], 1);
}

__global__ void fill_kernel(const int* __restrict__ idx, const float* __restrict__ w,
                            const int* __restrict__ cnt, int* __restrict__ fill,
                            int* __restrict__ rows, float* __restrict__ wts,
                            int* __restrict__ inv) {
  int i = blockIdx.x * blockDim.x + threadIdx.x;
  if (i < NPAIR) {
    int e = idx[i];
    int base = 0, acc = 0;
#pragma unroll
    for (int k = 0; k < NEXP; ++k) {
      if (k == e) base = acc;
      acc += cnt[k];
    }
    int p = atomicAdd(&fill[e], 1);
    int pos = base + p;
    rows[pos] = i >> 1;       // token id (K=2)
    wts[pos] = w[i];
    inv[i] = pos;
  }
}

// ---------------- GEMM1: h = silu(x@Wg^T) * (x@Wu^T) ----------------
// (256,2) / VGPR 100 is the proven point (207 us). (256,3) caps VGPR at 84
// and costs +55 us (measured twice, rounds 2 and 5). Do not change.
__launch_bounds__(256, 2)
__global__ void gemm1_kernel(const unsigned short* __restrict__ xb,
                             const unsigned short* __restrict__ wgb,
                             const unsigned short* __restrict__ wub,
                             const int* __restrict__ cnt, const int* __restrict__ rows,
                             unsigned short* __restrict__ hbuf) {
  TileInfo ti;
  if (!tile_lookup(cnt, blockIdx.y, ti)) return;
  const int tid = threadIdx.x;
  const int e = ti.e, ts = ti.ts, segBase = ti.segBase, segN = ti.segN;
  const int ncol0 = blockIdx.x * BN;

  __shared__ unsigned short lds[2][3][BM][BK];   // A, Bg, Bu double-buffered: 48 KiB
  __shared__ int rows_s[BM];

  if (tid < BM) {
    int r = ts + tid;
    rows_s[tid] = rows[segBase + (r < segN ? r : 0)];
  }
  __syncthreads();

  const int r0 = tid >> 2, r1 = 64 + (tid >> 2);
  const int kq = (tid & 3) * 8;   // bf16 elements
  const int tok0 = rows_s[r0], tok1 = rows_s[r1];
  const unsigned short* ag0 = xb + (size_t)tok0 * D_IN + kq;
  const unsigned short* ag1 = xb + (size_t)tok1 * D_IN + kq;
  const unsigned short* wge = wgb + (size_t)e * H_DIM * D_IN;
  const unsigned short* wue = wub + (size_t)e * H_DIM * D_IN;
  const unsigned short* bg0 = wge + (size_t)(ncol0 + r0) * D_IN + kq;
  const unsigned short* bg1 = wge + (size_t)(ncol0 + r1) * D_IN + kq;
  const unsigned short* bu0 = wue + (size_t)(ncol0 + r0) * D_IN + kq;
  const unsigned short* bu1 = wue + (size_t)(ncol0 + r1) * D_IN + kq;

#define STAGE1(b, k0) do { \
    gload16(ag0 + (k0), &lds[b][0][r0][kq]); \
    gload16(ag1 + (k0), &lds[b][0][r1][kq]); \
    gload16(bg0 + (k0), &lds[b][1][r0][kq]); \
    gload16(bg1 + (k0), &lds[b][1][r1][kq]); \
    gload16(bu0 + (k0), &lds[b][2][r0][kq]); \
    gload16(bu1 + (k0), &lds[b][2][r1][kq]); \
  } while (0)

  f32x4 gacc[4][4] = {};
  f32x4 uacc[4][4] = {};
  const int lane = tid & 63, wid = tid >> 6;
  const int wm = (wid >> 1) * 64, wn = (wid & 1) * 64;
  const int fr = lane & 15, fq = lane >> 4;

  STAGE1(0, 0);
  __syncthreads();
  for (int kt = 0; kt < D_IN / BK; ++kt) {
    const int cur = kt & 1;
    if (kt + 1 < D_IN / BK) STAGE1(cur ^ 1, (kt + 1) * BK);
    bf16x8 af[4], bgf[4], buf_[4];
#pragma unroll
    for (int mf = 0; mf < 4; ++mf) af[mf]   = *(const bf16x8*)&lds[cur][0][wm + mf * 16 + fr][fq * 8];
#pragma unroll
    for (int nf = 0; nf < 4; ++nf) bgf[nf]  = *(const bf16x8*)&lds[cur][1][wn + nf * 16 + fr][fq * 8];
#pragma unroll
    for (int nf = 0; nf < 4; ++nf) buf_[nf] = *(const bf16x8*)&lds[cur][2][wn + nf * 16 + fr][fq * 8];
#pragma unroll
    for (int mf = 0; mf < 4; ++mf)
#pragma unroll
      for (int nf = 0; nf < 4; ++nf) {
        gacc[mf][nf] = __builtin_amdgcn_mfma_f32_16x16x32_bf16(af[mf], bgf[nf],  gacc[mf][nf], 0, 0, 0);
        uacc[mf][nf] = __builtin_amdgcn_mfma_f32_16x16x32_bf16(af[mf], buf_[nf], uacc[mf][nf], 0, 0, 0);
      }
    __syncthreads();
  }
#undef STAGE1

#pragma unroll
  for (int mf = 0; mf < 4; ++mf)
#pragma unroll
    for (int i = 0; i < 4; ++i) {
      int rloc = wm + mf * 16 + fq * 4 + i;
      int rseg = ts + rloc;
      if (rseg < segN) {
        size_t base = (size_t)(segBase + rseg) * H_DIM + ncol0 + wn;
#pragma unroll
        for (int nf = 0; nf < 4; ++nf) {
          float g = gacc[mf][nf][i], u = uacc[mf][nf][i];
          float h = g / (1.f + __expf(-g)) * u;   // silu(g)*u
          hbuf[base + nf * 16 + fr] = f2bf(h);
        }
      }
    }
}

// ---------------- GEMM2: wout[pos] = w * (h @ Wd^T) ----------------
// BN=128 @ (256,4) is the proven point; BN=256 @ (256,2) costs +40 us
// (round 5). Only delta vs round 3: bf16 output stores.
__launch_bounds__(256, 4)
__global__ void gemm2_kernel(const unsigned short* __restrict__ hbuf,
                             const unsigned short* __restrict__ wdb,
                             const int* __restrict__ cnt,
                             const float* __restrict__ wts, unsigned short* __restrict__ wout) {
  TileInfo ti;
  if (!tile_lookup(cnt, blockIdx.y, ti)) return;
  const int tid = threadIdx.x;
  const int e = ti.e, ts = ti.ts, segBase = ti.segBase, segN = ti.segN;
  const int ncol0 = blockIdx.x * BN;

  __shared__ unsigned short lds[2][2][BM][BK];   // 32 KiB

  const int r0 = tid >> 2, r1 = 64 + (tid >> 2);
  const int kq = (tid & 3) * 8;
  int ar0 = ts + r0; if (ar0 >= segN) ar0 = segN - 1;
  int ar1 = ts + r1; if (ar1 >= segN) ar1 = segN - 1;
  const unsigned short* ag0 = hbuf + (size_t)(segBase + ar0) * H_DIM + kq;
  const unsigned short* ag1 = hbuf + (size_t)(segBase + ar1) * H_DIM + kq;
  const unsigned short* wde = wdb + (size_t)e * DOUT_ * H_DIM;
  const unsigned short* bg0 = wde + (size_t)(ncol0 + r0) * H_DIM + kq;
  const unsigned short* bg1 = wde + (size_t)(ncol0 + r1) * H_DIM + kq;

#define STAGE2(b, k0) do { \
    gload16(ag0 + (k0), &lds[b][0][r0][kq]); \
    gload16(ag1 + (k0), &lds[b][0][r1][kq]); \
    gload16(bg0 + (k0), &lds[b][1][r0][kq]); \
    gload16(bg1 + (k0), &lds[b][1][r1][kq]); \
  } while (0)

  f32x4 acc[4][4] = {};
  const int lane = tid & 63, wid = tid >> 6;
  const int wm = (wid >> 1) * 64, wn = (wid & 1) * 64;
  const int fr = lane & 15, fq = lane >> 4;

  STAGE2(0, 0);
  __syncthreads();
  for (int kt = 0; kt < H_DIM / BK; ++kt) {
    const int cur = kt & 1;
    if (kt + 1 < H_DIM / BK) STAGE2(cur ^ 1, (kt + 1) * BK);
    bf16x8 af[4], bf[4];
#pragma unroll
    for (int mf = 0; mf < 4; ++mf) af[mf] = *(const bf16x8*)&lds[cur][0][wm + mf * 16 + fr][fq * 8];
#pragma unroll
    for (int nf = 0; nf < 4; ++nf) bf[nf] = *(const bf16x8*)&lds[cur][1][wn + nf * 16 + fr][fq * 8];
#pragma unroll
    for (int mf = 0; mf < 4; ++mf)
#pragma unroll
      for (int nf = 0; nf < 4; ++nf)
        acc[mf][nf] = __builtin_amdgcn_mfma_f32_16x16x32_bf16(af[mf], bf[nf], acc[mf][nf], 0, 0, 0);
    __syncthreads();
  }
#undef STAGE2

#pragma unroll
  for (int mf = 0; mf < 4; ++mf)
#pragma unroll
    for (int i = 0; i < 4; ++i) {
      int rloc = wm + mf * 16 + fq * 4 + i;
      int rseg = ts + rloc;
      if (rseg < segN) {
        float w = wts[segBase + rseg];
        unsigned short* obase = wout + (size_t)(segBase + rseg) * DOUT_ + ncol0 + wn;
#pragma unroll
        for (int nf = 0; nf < 4; ++nf)
          obase[nf * 16 + fr] = f2bf(acc[mf][nf][i] * w);
      }
    }
}

// ---------------- combine: out[t] = wout[inv[2t]] + wout[inv[2t+1]] (bf16 in) ----
__global__ void combine_kernel(const unsigned short* __restrict__ wout, const int* __restrict__ inv,
                               float* __restrict__ out) {
  const int total = T_TOK * (DOUT_ / 4);           // 4-elem chunks
  for (int i = blockIdx.x * blockDim.x + threadIdx.x; i < total;
       i += gridDim.x * blockDim.x) {
    int t = i >> 8;                                 // DOUT/4 = 256 chunks per token
    int c4 = (i & 255) << 2;
    int p0 = inv[2 * t], p1 = inv[2 * t + 1];
    ushort4 a = *(const ushort4*)(wout + ((size_t)p0 << 10) + c4);
    ushort4 b = *(const ushort4*)(wout + ((size_t)p1 << 10) + c4);
    float4 r;
    r.x = bf2f(a.x) + bf2f(b.x);
    r.y = bf2f(a.y) + bf2f(b.y);
    r.z = bf2f(a.z) + bf2f(b.z);
    r.w = bf2f(a.w) + bf2f(b.w);
    *(float4*)(out + ((size_t)t << 10) + c4) = r;
  }
}

// ---------------- launch ----------------
extern "C" void kernel_launch(void* const* d_in, const int* in_sizes, int n_in,
                              void* d_out, int out_size, void* d_ws, size_t ws_size,
                              hipStream_t stream) {
  const float* x   = (const float*)d_in[0];
  const int*   idx = (const int*)d_in[1];
  const float* tkw = (const float*)d_in[2];
  const float* wg  = (const float*)d_in[3];
  const float* wu  = (const float*)d_in[4];
  const float* wd  = (const float*)d_in[5];
  float* out = (float*)d_out;

  char* p = (char*)d_ws;
  // wout (bf16, 33.5 MB) aliases xb+wgb: dead after gemm1, rewritten by
  // convert at the start of every call -> deterministic.
  unsigned short* wout = (unsigned short*)p;
  unsigned short* xb   = (unsigned short*)p; p += (size_t)T_TOK * D_IN * 2;
  unsigned short* wgb  = (unsigned short*)p; p += (size_t)NEXP * H_DIM * D_IN * 2;
  unsigned short* wub  = (unsigned short*)p; p += (size_t)NEXP * H_DIM * D_IN * 2;
  unsigned short* wdb  = (unsigned short*)p; p += (size_t)NEXP * DOUT_ * H_DIM * 2;
  unsigned short* hbuf = (unsigned short*)p; p += (size_t)NPAIR * H_DIM * 2;
  int*   rows = (int*)p;   p += NPAIR * 4;
  float* wts  = (float*)p; p += NPAIR * 4;
  int*   inv  = (int*)p;   p += NPAIR * 4;
  int* meta = (int*)p;                 // cnt[8] fill[8]
  int* cnt = meta;
  int* fill = meta + 8;

  hipMemsetAsync(meta, 0, 64, stream);                       // cnt + fill

  convert_kernel<<<2048, 256, 0, stream>>>(x, wg, wu, wd, xb, wgb, wub, wdb);
  count_kernel<<<NPAIR / 256, 256, 0, stream>>>(idx, cnt);
  fill_kernel<<<NPAIR / 256, 256, 0, stream>>>(idx, tkw, cnt, fill, rows, wts, inv);
  gemm1_kernel<<<dim3(H_DIM / BN, MAX_TILES), 256, 0, stream>>>(xb, wgb, wub, cnt, rows, hbuf);
  gemm2_kernel<<<dim3(DOUT_ / BN, MAX_TILES), 256, 0, stream>>>(hbuf, wdb, cnt, wts, wout);
  combine_kernel<<<2048, 256, 0, stream>>>(wout, inv, out);
}